// Round 4
// baseline (1312.906 us; speedup 1.0000x reference)
//
#include <hip/hip_runtime.h>
#include <cmath>

// ---------------------------------------------------------------------------
// PlainGNN: Q/K/V = x@W^T ; per-edge scores = leakyrelu(scale * sum_d D*(K_i-Q_j)^2)
// (self edges: K^T diag(D) Q) ; segment-softmax over destination row ;
// out[row] += alpha * V[col].
// N=100000, E=1600000, IN_F=128, HEADS=4, D_K=32.
//
// R1: edge_aggregate atomic-bound (204.8M atomicAdds, 800MB write-through).
// R2/R3: CSR by destination, one wave per node, no output atomics. 1470->1228us.
// R4: qkv_gemm was LDS-scalar-read-bound (VALUBusy 31%, 1.4e7 bank conflicts).
//     -> k-major LDS tiles + ds_read_b128 + 8x8 acc. Also fold exp into
//     edge_scores (scores bounded, max-subtraction unnecessary) and drop the
//     smax pass + edge_expsum dispatch entirely.
// ---------------------------------------------------------------------------

#define HEADS 4
#define DK 32
#define FDIM 128

// ssum=0 over N*H ; deg=0, cursor=0 over N.
__global__ __launch_bounds__(256) void init_buffers(
    float* __restrict__ ssum, int* __restrict__ deg, int* __restrict__ cursor,
    int n_nh, int n)
{
    int gid = blockIdx.x * 256 + threadIdx.x;
    if (gid < n_nh) ssum[gid] = 0.0f;
    if (gid < n)    { deg[gid] = 0; cursor[gid] = 0; }
}

// Fused QKV projection. Block = 256 threads computes a 128-node x 128-out tile
// for one of {Wq,Wk,Wv} (blockIdx.y). k-major LDS tiles (stride 132 floats
// keeps float4 alignment) -> inner loop is 4x ds_read_b128 + 64 FMA per k.
__global__ __launch_bounds__(256, 4) void qkv_gemm(
    const float* __restrict__ x, const float* __restrict__ Wq,
    const float* __restrict__ Wk, const float* __restrict__ Wv,
    float* __restrict__ Q, float* __restrict__ K, float* __restrict__ V, int N)
{
    __shared__ float xs[32][132];
    __shared__ float ws[32][132];
    const float* __restrict__ W = (blockIdx.y == 0) ? Wq : (blockIdx.y == 1 ? Wk : Wv);
    float* __restrict__ O = (blockIdx.y == 0) ? Q : (blockIdx.y == 1 ? K : V);
    const int n0 = blockIdx.x * 128;
    const int tid = threadIdx.x;
    const int tm = (tid & 15) * 8;   // 8 nodes per thread
    const int tn = (tid >> 4) * 8;   // 8 outputs per thread

    float acc[8][8];
#pragma unroll
    for (int i = 0; i < 8; ++i)
#pragma unroll
        for (int j = 0; j < 8; ++j) acc[i][j] = 0.0f;

    for (int kt = 0; kt < FDIM; kt += 32) {
        // Stage 128 rows x 32 ks of x and W, transposed into k-major LDS.
#pragma unroll
        for (int p = 0; p < 4; ++p) {
            int f = tid + p * 256;       // float4 id: 8 per row
            int r = f >> 3;              // row 0..127 (node / out-row)
            int kq = (f & 7) * 4;        // k offset 0,4,..,28
            int n = n0 + r;
            float4 v = make_float4(0.f, 0.f, 0.f, 0.f);
            if (n < N) v = *reinterpret_cast<const float4*>(x + (size_t)n * FDIM + kt + kq);
            xs[kq + 0][r] = v.x; xs[kq + 1][r] = v.y;
            xs[kq + 2][r] = v.z; xs[kq + 3][r] = v.w;
            float4 w4 = *reinterpret_cast<const float4*>(W + r * FDIM + kt + kq);
            ws[kq + 0][r] = w4.x; ws[kq + 1][r] = w4.y;
            ws[kq + 2][r] = w4.z; ws[kq + 3][r] = w4.w;
        }
        __syncthreads();
#pragma unroll
        for (int k = 0; k < 32; ++k) {
            float4 a0 = *reinterpret_cast<const float4*>(&xs[k][tm]);
            float4 a1 = *reinterpret_cast<const float4*>(&xs[k][tm + 4]);
            float4 b0 = *reinterpret_cast<const float4*>(&ws[k][tn]);
            float4 b1 = *reinterpret_cast<const float4*>(&ws[k][tn + 4]);
            float av[8] = {a0.x, a0.y, a0.z, a0.w, a1.x, a1.y, a1.z, a1.w};
            float bv[8] = {b0.x, b0.y, b0.z, b0.w, b1.x, b1.y, b1.z, b1.w};
#pragma unroll
            for (int i = 0; i < 8; ++i)
#pragma unroll
                for (int j = 0; j < 8; ++j) acc[i][j] += av[i] * bv[j];
        }
        __syncthreads();
    }

#pragma unroll
    for (int i = 0; i < 8; ++i) {
        int n = n0 + tm + i;
        if (n < N) {
            *reinterpret_cast<float4*>(O + (size_t)n * FDIM + tn) =
                make_float4(acc[i][0], acc[i][1], acc[i][2], acc[i][3]);
            *reinterpret_cast<float4*>(O + (size_t)n * FDIM + tn + 4) =
                make_float4(acc[i][4], acc[i][5], acc[i][6], acc[i][7]);
        }
    }
}

// One thread per (edge, head): 32-dim weighted dot, leaky-relu, exp, segment
// sum via atomics. No max-subtraction: |z| is bounded (~20), exp is safe in
// fp32 and the alpha ratio is mathematically identical.
__global__ __launch_bounds__(256) void edge_scores(
    const float* __restrict__ Q, const float* __restrict__ K,
    const float* __restrict__ D,
    const int* __restrict__ row, const int* __restrict__ col,
    float* __restrict__ score, float* __restrict__ ssum,
    int E, int N)
{
    __shared__ float Dl[HEADS * DK];
    if (threadIdx.x < HEADS * DK) Dl[threadIdx.x] = D[threadIdx.x];
    __syncthreads();
    int gid = blockIdx.x * 256 + threadIdx.x;
    if (gid >= E * HEADS) return;
    int e = gid >> 2, h = gid & 3;
    int r = row[e], c = col[e];
    if ((unsigned)r >= (unsigned)N || (unsigned)c >= (unsigned)N) return;

    const float4* kp = reinterpret_cast<const float4*>(K + (size_t)r * FDIM + h * DK);
    const float4* qp = reinterpret_cast<const float4*>(Q + (size_t)c * FDIM + h * DK);
    const float4* dp = reinterpret_cast<const float4*>(Dl + h * DK);
    float s = 0.0f;
    if (r != c) {
#pragma unroll
        for (int i = 0; i < DK / 4; ++i) {
            float4 kv = kp[i], qv = qp[i], dv = dp[i];
            float dx = kv.x - qv.x, dy = kv.y - qv.y;
            float dz = kv.z - qv.z, dw = kv.w - qv.w;
            s += dv.x * dx * dx + dv.y * dy * dy + dv.z * dz * dz + dv.w * dw * dw;
        }
    } else {
#pragma unroll
        for (int i = 0; i < DK / 4; ++i) {
            float4 kv = kp[i], qv = qp[i], dv = dp[i];
            s += dv.x * kv.x * qv.x + dv.y * kv.y * qv.y
               + dv.z * kv.z * qv.z + dv.w * kv.w * qv.w;
        }
    }
    float z = s * 0.17677669529663687f;   // 1/sqrt(32)
    z = (z > 0.0f) ? z : 0.2f * z;        // leaky_relu slope 0.2
    float ex = __expf(z);
    score[gid] = ex;
    atomicAdd(&ssum[r * HEADS + h], ex);
}

// ---- CSR build: degree histogram -> exclusive scan -> scatter fill ----

__global__ __launch_bounds__(256) void deg_count(
    const int* __restrict__ row, int* __restrict__ deg, int E, int N)
{
    int gid = blockIdx.x * 256 + threadIdx.x;
    if (gid >= E) return;
    int r = row[gid];
    if ((unsigned)r < (unsigned)N) atomicAdd(&deg[r], 1);
}

// Block-level exclusive scan over tiles of 1024 (256 thr x 4). Writes per-tile
// exclusive offsets into off[], per-tile totals into bsum[].
__global__ __launch_bounds__(256) void scan1(
    const int* __restrict__ deg, int* __restrict__ off, int* __restrict__ bsum, int N)
{
    __shared__ int lds[256];
    const int base = blockIdx.x * 1024;
    const int tid = threadIdx.x;
    int v[4];
    int tsum = 0;
#pragma unroll
    for (int i = 0; i < 4; ++i) {
        int idx = base + tid * 4 + i;
        v[i] = (idx < N) ? deg[idx] : 0;
        tsum += v[i];
    }
    lds[tid] = tsum;
    __syncthreads();
    for (int ofs = 1; ofs < 256; ofs <<= 1) {
        int t = (tid >= ofs) ? lds[tid - ofs] : 0;
        __syncthreads();
        lds[tid] += t;
        __syncthreads();
    }
    int run = lds[tid] - tsum;
    if (tid == 255) bsum[blockIdx.x] = lds[255];
#pragma unroll
    for (int i = 0; i < 4; ++i) {
        int idx = base + tid * 4 + i;
        if (idx < N) off[idx] = run;
        run += v[i];
    }
}

// Single-block exclusive scan of per-tile totals (nb <= 256; N=100000 -> 98).
__global__ __launch_bounds__(256) void scan2(int* __restrict__ bsum, int nb)
{
    __shared__ int lds[256];
    int tid = threadIdx.x;
    int v = (tid < nb) ? bsum[tid] : 0;
    lds[tid] = v;
    __syncthreads();
    for (int ofs = 1; ofs < 256; ofs <<= 1) {
        int t = (tid >= ofs) ? lds[tid - ofs] : 0;
        __syncthreads();
        lds[tid] += t;
        __syncthreads();
    }
    if (tid < nb) bsum[tid] = lds[tid] - v;
}

__global__ __launch_bounds__(256) void scan3(
    int* __restrict__ off, const int* __restrict__ bsum, int N, int E)
{
    int gid = blockIdx.x * 256 + threadIdx.x;
    if (gid < N) off[gid] += bsum[gid >> 10];
    if (gid == 0) off[N] = E;
}

__global__ __launch_bounds__(256) void fill_csr(
    const int* __restrict__ row, const int* __restrict__ off,
    int* __restrict__ cursor, int* __restrict__ csr, int E, int N)
{
    int e = blockIdx.x * 256 + threadIdx.x;
    if (e >= E) return;
    int r = row[e];
    if ((unsigned)r >= (unsigned)N) return;
    int p = atomicAdd(&cursor[r], 1);
    csr[off[r] + p] = e;
}

// One wave per destination node. lane -> dims (2*lane, 2*lane+1), head =
// lane>>4. Register accumulation over CSR edge list, coalesced float2 store.
__global__ __launch_bounds__(256) void aggregate_csr(
    const int* __restrict__ col, const int* __restrict__ off,
    const int* __restrict__ csr, const float* __restrict__ score,
    const float* __restrict__ ssum, const float* __restrict__ V,
    float* __restrict__ out, int N)
{
    int node = blockIdx.x * 4 + (threadIdx.x >> 6);
    if (node >= N) return;
    int lane = threadIdx.x & 63;
    int h = lane >> 4;
    int d = lane * 2;
    float inv = 1.0f / (ssum[node * HEADS + h] + 1e-16f);
    int j0 = off[node], j1 = off[node + 1];
    float a0 = 0.0f, a1 = 0.0f;
    for (int j = j0; j < j1; ++j) {
        int e = csr[j];
        int c = col[e];
        float a = score[e * HEADS + h] * inv;
        const float2 v = *reinterpret_cast<const float2*>(V + (size_t)c * FDIM + d);
        a0 += a * v.x;
        a1 += a * v.y;
    }
    *reinterpret_cast<float2*>(out + (size_t)node * FDIM + d) = make_float2(a0, a1);
}

extern "C" void kernel_launch(void* const* d_in, const int* in_sizes, int n_in,
                              void* d_out, int out_size, void* d_ws, size_t ws_size,
                              hipStream_t stream) {
    const float* x  = (const float*)d_in[0];
    const float* Wq = (const float*)d_in[1];
    const float* Wk = (const float*)d_in[2];
    const float* Wv = (const float*)d_in[3];
    const float* D  = (const float*)d_in[4];
    const int*  edge = (const int*)d_in[5];
    float* out = (float*)d_out;

    const int N = in_sizes[0] / FDIM;
    const int E = in_sizes[5] / 2;
    const int* row = edge;       // edge_index[0] = destination (segment id)
    const int* col = edge + E;   // edge_index[1] = source of Q_j / V

    // Workspace layout: Q | K | V | score | ssum | deg | cursor | off | bsum | csr
    float* ws    = (float*)d_ws;
    float* Q     = ws;
    float* K     = Q + (size_t)N * FDIM;
    float* V     = K + (size_t)N * FDIM;
    float* score = V + (size_t)N * FDIM;
    float* ssum  = score + (size_t)E * HEADS;
    int* deg     = (int*)(ssum + (size_t)N * HEADS);
    int* cursor  = deg + N;
    int* off     = cursor + N;          // N+1 entries
    int* bsum    = off + (N + 1);       // up to 256 entries
    int* csr     = bsum + 256;          // E entries

    const int n_nh = N * HEADS;
    const int ne_h = E * HEADS;
    const int nb   = (N + 1023) / 1024;

    init_buffers<<<(n_nh + 255) / 256, 256, 0, stream>>>(ssum, deg, cursor, n_nh, N);

    dim3 ggrid((N + 127) / 128, 3);
    qkv_gemm<<<ggrid, 256, 0, stream>>>(x, Wq, Wk, Wv, Q, K, V, N);

    deg_count<<<(E + 255) / 256, 256, 0, stream>>>(row, deg, E, N);
    scan1<<<nb, 256, 0, stream>>>(deg, off, bsum, N);
    scan2<<<1, 256, 0, stream>>>(bsum, nb);
    scan3<<<(N + 255) / 256, 256, 0, stream>>>(off, bsum, N, E);
    fill_csr<<<(E + 255) / 256, 256, 0, stream>>>(row, off, cursor, csr, E, N);

    edge_scores<<<(ne_h + 255) / 256, 256, 0, stream>>>(Q, K, D, row, col, score, ssum, E, N);

    aggregate_csr<<<(N + 3) / 4, 256, 0, stream>>>(
        col, off, csr, score, ssum, V, out, N);
}

// Round 5
// 1041.910 us; speedup vs baseline: 1.2601x; 1.2601x over previous
//
#include <hip/hip_runtime.h>
#include <cmath>

// ---------------------------------------------------------------------------
// PlainGNN: Q/K/V = x@W^T ; per-edge scores = leakyrelu(scale * sum_d D*(K_i-Q_j)^2)
// (self edges: K^T diag(D) Q) ; segment-softmax over destination row ;
// out[row] += alpha * V[col].
// N=100000, E=1600000, IN_F=128, HEADS=4, D_K=32.
//
// R1: edge_aggregate atomic-bound (204.8M atomicAdds, 800MB write-through).
// R2/R3: CSR by destination, one wave per node, no output atomics. 1470->1228us.
// R4: k-major LDS + 8x8 acc + fused exp into edge_scores. BUT
//     __launch_bounds__(256,4) capped VGPR at 64 -> 64-float accumulator
//     spilled to scratch: 2GB traffic/dispatch, 497us. R5 removes the cap
//     (plain launch_bounds(256)); structure unchanged.
// ---------------------------------------------------------------------------

#define HEADS 4
#define DK 32
#define FDIM 128

// ssum=0 over N*H ; deg=0, cursor=0 over N.
__global__ __launch_bounds__(256) void init_buffers(
    float* __restrict__ ssum, int* __restrict__ deg, int* __restrict__ cursor,
    int n_nh, int n)
{
    int gid = blockIdx.x * 256 + threadIdx.x;
    if (gid < n_nh) ssum[gid] = 0.0f;
    if (gid < n)    { deg[gid] = 0; cursor[gid] = 0; }
}

// Fused QKV projection. Block = 256 threads computes a 128-node x 128-out tile
// for one of {Wq,Wk,Wv} (blockIdx.y). k-major LDS tiles (stride 132 floats
// keeps float4 alignment) -> inner loop is 4x ds_read_b128 + 64 FMA per k.
// NOTE: no min-waves in launch_bounds — (256,4) forced VGPR=64 and spilled
// the 8x8 accumulator to scratch (R4: 2GB traffic, 497us).
__global__ __launch_bounds__(256) void qkv_gemm(
    const float* __restrict__ x, const float* __restrict__ Wq,
    const float* __restrict__ Wk, const float* __restrict__ Wv,
    float* __restrict__ Q, float* __restrict__ K, float* __restrict__ V, int N)
{
    __shared__ float xs[32][132];
    __shared__ float ws[32][132];
    const float* __restrict__ W = (blockIdx.y == 0) ? Wq : (blockIdx.y == 1 ? Wk : Wv);
    float* __restrict__ O = (blockIdx.y == 0) ? Q : (blockIdx.y == 1 ? K : V);
    const int n0 = blockIdx.x * 128;
    const int tid = threadIdx.x;
    const int tm = (tid & 15) * 8;   // 8 nodes per thread
    const int tn = (tid >> 4) * 8;   // 8 outputs per thread

    float acc[8][8];
#pragma unroll
    for (int i = 0; i < 8; ++i)
#pragma unroll
        for (int j = 0; j < 8; ++j) acc[i][j] = 0.0f;

    for (int kt = 0; kt < FDIM; kt += 32) {
        // Stage 128 rows x 32 ks of x and W, transposed into k-major LDS.
#pragma unroll
        for (int p = 0; p < 4; ++p) {
            int f = tid + p * 256;       // float4 id: 8 per row
            int r = f >> 3;              // row 0..127 (node / out-row)
            int kq = (f & 7) * 4;        // k offset 0,4,..,28
            int n = n0 + r;
            float4 v = make_float4(0.f, 0.f, 0.f, 0.f);
            if (n < N) v = *reinterpret_cast<const float4*>(x + (size_t)n * FDIM + kt + kq);
            xs[kq + 0][r] = v.x; xs[kq + 1][r] = v.y;
            xs[kq + 2][r] = v.z; xs[kq + 3][r] = v.w;
            float4 w4 = *reinterpret_cast<const float4*>(W + r * FDIM + kt + kq);
            ws[kq + 0][r] = w4.x; ws[kq + 1][r] = w4.y;
            ws[kq + 2][r] = w4.z; ws[kq + 3][r] = w4.w;
        }
        __syncthreads();
#pragma unroll
        for (int k = 0; k < 32; ++k) {
            float4 a0 = *reinterpret_cast<const float4*>(&xs[k][tm]);
            float4 a1 = *reinterpret_cast<const float4*>(&xs[k][tm + 4]);
            float4 b0 = *reinterpret_cast<const float4*>(&ws[k][tn]);
            float4 b1 = *reinterpret_cast<const float4*>(&ws[k][tn + 4]);
            float av[8] = {a0.x, a0.y, a0.z, a0.w, a1.x, a1.y, a1.z, a1.w};
            float bv[8] = {b0.x, b0.y, b0.z, b0.w, b1.x, b1.y, b1.z, b1.w};
#pragma unroll
            for (int i = 0; i < 8; ++i)
#pragma unroll
                for (int j = 0; j < 8; ++j) acc[i][j] += av[i] * bv[j];
        }
        __syncthreads();
    }

#pragma unroll
    for (int i = 0; i < 8; ++i) {
        int n = n0 + tm + i;
        if (n < N) {
            *reinterpret_cast<float4*>(O + (size_t)n * FDIM + tn) =
                make_float4(acc[i][0], acc[i][1], acc[i][2], acc[i][3]);
            *reinterpret_cast<float4*>(O + (size_t)n * FDIM + tn + 4) =
                make_float4(acc[i][4], acc[i][5], acc[i][6], acc[i][7]);
        }
    }
}

// One thread per (edge, head): 32-dim weighted dot, leaky-relu, exp, segment
// sum via atomics. No max-subtraction: |z| is bounded (~20), exp is safe in
// fp32 and the alpha ratio is mathematically identical.
__global__ __launch_bounds__(256) void edge_scores(
    const float* __restrict__ Q, const float* __restrict__ K,
    const float* __restrict__ D,
    const int* __restrict__ row, const int* __restrict__ col,
    float* __restrict__ score, float* __restrict__ ssum,
    int E, int N)
{
    __shared__ float Dl[HEADS * DK];
    if (threadIdx.x < HEADS * DK) Dl[threadIdx.x] = D[threadIdx.x];
    __syncthreads();
    int gid = blockIdx.x * 256 + threadIdx.x;
    if (gid >= E * HEADS) return;
    int e = gid >> 2, h = gid & 3;
    int r = row[e], c = col[e];
    if ((unsigned)r >= (unsigned)N || (unsigned)c >= (unsigned)N) return;

    const float4* kp = reinterpret_cast<const float4*>(K + (size_t)r * FDIM + h * DK);
    const float4* qp = reinterpret_cast<const float4*>(Q + (size_t)c * FDIM + h * DK);
    const float4* dp = reinterpret_cast<const float4*>(Dl + h * DK);
    float s = 0.0f;
    if (r != c) {
#pragma unroll
        for (int i = 0; i < DK / 4; ++i) {
            float4 kv = kp[i], qv = qp[i], dv = dp[i];
            float dx = kv.x - qv.x, dy = kv.y - qv.y;
            float dz = kv.z - qv.z, dw = kv.w - qv.w;
            s += dv.x * dx * dx + dv.y * dy * dy + dv.z * dz * dz + dv.w * dw * dw;
        }
    } else {
#pragma unroll
        for (int i = 0; i < DK / 4; ++i) {
            float4 kv = kp[i], qv = qp[i], dv = dp[i];
            s += dv.x * kv.x * qv.x + dv.y * kv.y * qv.y
               + dv.z * kv.z * qv.z + dv.w * kv.w * qv.w;
        }
    }
    float z = s * 0.17677669529663687f;   // 1/sqrt(32)
    z = (z > 0.0f) ? z : 0.2f * z;        // leaky_relu slope 0.2
    float ex = __expf(z);
    score[gid] = ex;
    atomicAdd(&ssum[r * HEADS + h], ex);
}

// ---- CSR build: degree histogram -> exclusive scan -> scatter fill ----

__global__ __launch_bounds__(256) void deg_count(
    const int* __restrict__ row, int* __restrict__ deg, int E, int N)
{
    int gid = blockIdx.x * 256 + threadIdx.x;
    if (gid >= E) return;
    int r = row[gid];
    if ((unsigned)r < (unsigned)N) atomicAdd(&deg[r], 1);
}

// Block-level exclusive scan over tiles of 1024 (256 thr x 4). Writes per-tile
// exclusive offsets into off[], per-tile totals into bsum[].
__global__ __launch_bounds__(256) void scan1(
    const int* __restrict__ deg, int* __restrict__ off, int* __restrict__ bsum, int N)
{
    __shared__ int lds[256];
    const int base = blockIdx.x * 1024;
    const int tid = threadIdx.x;
    int v[4];
    int tsum = 0;
#pragma unroll
    for (int i = 0; i < 4; ++i) {
        int idx = base + tid * 4 + i;
        v[i] = (idx < N) ? deg[idx] : 0;
        tsum += v[i];
    }
    lds[tid] = tsum;
    __syncthreads();
    for (int ofs = 1; ofs < 256; ofs <<= 1) {
        int t = (tid >= ofs) ? lds[tid - ofs] : 0;
        __syncthreads();
        lds[tid] += t;
        __syncthreads();
    }
    int run = lds[tid] - tsum;
    if (tid == 255) bsum[blockIdx.x] = lds[255];
#pragma unroll
    for (int i = 0; i < 4; ++i) {
        int idx = base + tid * 4 + i;
        if (idx < N) off[idx] = run;
        run += v[i];
    }
}

// Single-block exclusive scan of per-tile totals (nb <= 256; N=100000 -> 98).
__global__ __launch_bounds__(256) void scan2(int* __restrict__ bsum, int nb)
{
    __shared__ int lds[256];
    int tid = threadIdx.x;
    int v = (tid < nb) ? bsum[tid] : 0;
    lds[tid] = v;
    __syncthreads();
    for (int ofs = 1; ofs < 256; ofs <<= 1) {
        int t = (tid >= ofs) ? lds[tid - ofs] : 0;
        __syncthreads();
        lds[tid] += t;
        __syncthreads();
    }
    if (tid < nb) bsum[tid] = lds[tid] - v;
}

__global__ __launch_bounds__(256) void scan3(
    int* __restrict__ off, const int* __restrict__ bsum, int N, int E)
{
    int gid = blockIdx.x * 256 + threadIdx.x;
    if (gid < N) off[gid] += bsum[gid >> 10];
    if (gid == 0) off[N] = E;
}

__global__ __launch_bounds__(256) void fill_csr(
    const int* __restrict__ row, const int* __restrict__ off,
    int* __restrict__ cursor, int* __restrict__ csr, int E, int N)
{
    int e = blockIdx.x * 256 + threadIdx.x;
    if (e >= E) return;
    int r = row[e];
    if ((unsigned)r >= (unsigned)N) return;
    int p = atomicAdd(&cursor[r], 1);
    csr[off[r] + p] = e;
}

// One wave per destination node. lane -> dims (2*lane, 2*lane+1), head =
// lane>>4. Register accumulation over CSR edge list, coalesced float2 store.
__global__ __launch_bounds__(256) void aggregate_csr(
    const int* __restrict__ col, const int* __restrict__ off,
    const int* __restrict__ csr, const float* __restrict__ score,
    const float* __restrict__ ssum, const float* __restrict__ V,
    float* __restrict__ out, int N)
{
    int node = blockIdx.x * 4 + (threadIdx.x >> 6);
    if (node >= N) return;
    int lane = threadIdx.x & 63;
    int h = lane >> 4;
    int d = lane * 2;
    float inv = 1.0f / (ssum[node * HEADS + h] + 1e-16f);
    int j0 = off[node], j1 = off[node + 1];
    float a0 = 0.0f, a1 = 0.0f;
    for (int j = j0; j < j1; ++j) {
        int e = csr[j];
        int c = col[e];
        float a = score[e * HEADS + h] * inv;
        const float2 v = *reinterpret_cast<const float2*>(V + (size_t)c * FDIM + d);
        a0 += a * v.x;
        a1 += a * v.y;
    }
    *reinterpret_cast<float2*>(out + (size_t)node * FDIM + d) = make_float2(a0, a1);
}

extern "C" void kernel_launch(void* const* d_in, const int* in_sizes, int n_in,
                              void* d_out, int out_size, void* d_ws, size_t ws_size,
                              hipStream_t stream) {
    const float* x  = (const float*)d_in[0];
    const float* Wq = (const float*)d_in[1];
    const float* Wk = (const float*)d_in[2];
    const float* Wv = (const float*)d_in[3];
    const float* D  = (const float*)d_in[4];
    const int*  edge = (const int*)d_in[5];
    float* out = (float*)d_out;

    const int N = in_sizes[0] / FDIM;
    const int E = in_sizes[5] / 2;
    const int* row = edge;       // edge_index[0] = destination (segment id)
    const int* col = edge + E;   // edge_index[1] = source of Q_j / V

    // Workspace layout: Q | K | V | score | ssum | deg | cursor | off | bsum | csr
    float* ws    = (float*)d_ws;
    float* Q     = ws;
    float* K     = Q + (size_t)N * FDIM;
    float* V     = K + (size_t)N * FDIM;
    float* score = V + (size_t)N * FDIM;
    float* ssum  = score + (size_t)E * HEADS;
    int* deg     = (int*)(ssum + (size_t)N * HEADS);
    int* cursor  = deg + N;
    int* off     = cursor + N;          // N+1 entries
    int* bsum    = off + (N + 1);       // up to 256 entries
    int* csr     = bsum + 256;          // E entries

    const int n_nh = N * HEADS;
    const int ne_h = E * HEADS;
    const int nb   = (N + 1023) / 1024;

    init_buffers<<<(n_nh + 255) / 256, 256, 0, stream>>>(ssum, deg, cursor, n_nh, N);

    dim3 ggrid((N + 127) / 128, 3);
    qkv_gemm<<<ggrid, 256, 0, stream>>>(x, Wq, Wk, Wv, Q, K, V, N);

    deg_count<<<(E + 255) / 256, 256, 0, stream>>>(row, deg, E, N);
    scan1<<<nb, 256, 0, stream>>>(deg, off, bsum, N);
    scan2<<<1, 256, 0, stream>>>(bsum, nb);
    scan3<<<(N + 255) / 256, 256, 0, stream>>>(off, bsum, N, E);
    fill_csr<<<(E + 255) / 256, 256, 0, stream>>>(row, off, cursor, csr, E, N);

    edge_scores<<<(ne_h + 255) / 256, 256, 0, stream>>>(Q, K, D, row, col, score, ssum, E, N);

    aggregate_csr<<<(N + 3) / 4, 256, 0, stream>>>(
        col, off, csr, score, ssum, V, out, N);
}

// Round 6
// 779.291 us; speedup vs baseline: 1.6847x; 1.3370x over previous
//
#include <hip/hip_runtime.h>
#include <cmath>

// ---------------------------------------------------------------------------
// PlainGNN: Q/K/V = x@W^T ; per-edge scores = leakyrelu(scale * sum_d D*(K_i-Q_j)^2)
// (self edges: K^T diag(D) Q) ; segment-softmax over destination row ;
// out[row] += alpha * V[col].
// N=100000, E=1600000, IN_F=128, HEADS=4, D_K=32.
//
// R1: edge_aggregate atomic-bound (204.8M atomicAdds). R2/R3: CSR by dest,
// one wave per node. R4: (256,4) launch-bounds spilled acc -> 2GB scratch.
// R5: cap removed -> 1042us; edge_scores now top (310us, gather-bound,
// 790MB HBM). R6: fuse scores+exp+aggregate into ONE CSR kernel: K[node]+D
// in regs, gather Q|V (interleaved QV[N][256] -> one 1KB contiguous gather
// per edge), shfl_xor head-reduce, online ssum, divide at end. Deletes
// edge_scores pass, score buffer round-trip, ssum atomics.
// ---------------------------------------------------------------------------

#define HEADS 4
#define DK 32
#define FDIM 128

// deg=0, cursor=0 over N.
__global__ __launch_bounds__(256) void init_buffers(
    int* __restrict__ deg, int* __restrict__ cursor, int n)
{
    int gid = blockIdx.x * 256 + threadIdx.x;
    if (gid < n) { deg[gid] = 0; cursor[gid] = 0; }
}

// Fused QKV projection. Block = 256 threads computes a 128-node x 128-out tile
// for one of {Wq,Wk,Wv} (blockIdx.y). k-major LDS tiles (stride 132 floats
// keeps float4 alignment) -> inner loop is 4x ds_read_b128 + 64 FMA per k.
// Q and V write interleaved into QV[N][256] (Q at +0, V at +128); K dense.
// NOTE: plain launch_bounds(256) — (256,4) forced VGPR=64 and spilled (R4).
__global__ __launch_bounds__(256) void qkv_gemm(
    const float* __restrict__ x, const float* __restrict__ Wq,
    const float* __restrict__ Wk, const float* __restrict__ Wv,
    float* __restrict__ QV, float* __restrict__ Kb, int N)
{
    __shared__ float xs[32][132];
    __shared__ float ws[32][132];
    const float* __restrict__ W = (blockIdx.y == 0) ? Wq : (blockIdx.y == 1 ? Wk : Wv);
    float* __restrict__ O = (blockIdx.y == 1) ? Kb : QV;
    const int ostride = (blockIdx.y == 1) ? FDIM : 256;
    const int obase   = (blockIdx.y == 2) ? FDIM : 0;
    const int n0 = blockIdx.x * 128;
    const int tid = threadIdx.x;
    const int tm = (tid & 15) * 8;   // 8 nodes per thread
    const int tn = (tid >> 4) * 8;   // 8 outputs per thread

    float acc[8][8];
#pragma unroll
    for (int i = 0; i < 8; ++i)
#pragma unroll
        for (int j = 0; j < 8; ++j) acc[i][j] = 0.0f;

    for (int kt = 0; kt < FDIM; kt += 32) {
#pragma unroll
        for (int p = 0; p < 4; ++p) {
            int f = tid + p * 256;       // float4 id: 8 per row
            int r = f >> 3;              // row 0..127
            int kq = (f & 7) * 4;        // k offset
            int n = n0 + r;
            float4 v = make_float4(0.f, 0.f, 0.f, 0.f);
            if (n < N) v = *reinterpret_cast<const float4*>(x + (size_t)n * FDIM + kt + kq);
            xs[kq + 0][r] = v.x; xs[kq + 1][r] = v.y;
            xs[kq + 2][r] = v.z; xs[kq + 3][r] = v.w;
            float4 w4 = *reinterpret_cast<const float4*>(W + r * FDIM + kt + kq);
            ws[kq + 0][r] = w4.x; ws[kq + 1][r] = w4.y;
            ws[kq + 2][r] = w4.z; ws[kq + 3][r] = w4.w;
        }
        __syncthreads();
#pragma unroll
        for (int k = 0; k < 32; ++k) {
            float4 a0 = *reinterpret_cast<const float4*>(&xs[k][tm]);
            float4 a1 = *reinterpret_cast<const float4*>(&xs[k][tm + 4]);
            float4 b0 = *reinterpret_cast<const float4*>(&ws[k][tn]);
            float4 b1 = *reinterpret_cast<const float4*>(&ws[k][tn + 4]);
            float av[8] = {a0.x, a0.y, a0.z, a0.w, a1.x, a1.y, a1.z, a1.w};
            float bv[8] = {b0.x, b0.y, b0.z, b0.w, b1.x, b1.y, b1.z, b1.w};
#pragma unroll
            for (int i = 0; i < 8; ++i)
#pragma unroll
                for (int j = 0; j < 8; ++j) acc[i][j] += av[i] * bv[j];
        }
        __syncthreads();
    }

#pragma unroll
    for (int i = 0; i < 8; ++i) {
        int n = n0 + tm + i;
        if (n < N) {
            *reinterpret_cast<float4*>(O + (size_t)n * ostride + obase + tn) =
                make_float4(acc[i][0], acc[i][1], acc[i][2], acc[i][3]);
            *reinterpret_cast<float4*>(O + (size_t)n * ostride + obase + tn + 4) =
                make_float4(acc[i][4], acc[i][5], acc[i][6], acc[i][7]);
        }
    }
}

// ---- CSR build: degree histogram -> exclusive scan -> scatter fill ----

__global__ __launch_bounds__(256) void deg_count(
    const int* __restrict__ row, int* __restrict__ deg, int E, int N)
{
    int gid = blockIdx.x * 256 + threadIdx.x;
    if (gid >= E) return;
    int r = row[gid];
    if ((unsigned)r < (unsigned)N) atomicAdd(&deg[r], 1);
}

__global__ __launch_bounds__(256) void scan1(
    const int* __restrict__ deg, int* __restrict__ off, int* __restrict__ bsum, int N)
{
    __shared__ int lds[256];
    const int base = blockIdx.x * 1024;
    const int tid = threadIdx.x;
    int v[4];
    int tsum = 0;
#pragma unroll
    for (int i = 0; i < 4; ++i) {
        int idx = base + tid * 4 + i;
        v[i] = (idx < N) ? deg[idx] : 0;
        tsum += v[i];
    }
    lds[tid] = tsum;
    __syncthreads();
    for (int ofs = 1; ofs < 256; ofs <<= 1) {
        int t = (tid >= ofs) ? lds[tid - ofs] : 0;
        __syncthreads();
        lds[tid] += t;
        __syncthreads();
    }
    int run = lds[tid] - tsum;
    if (tid == 255) bsum[blockIdx.x] = lds[255];
#pragma unroll
    for (int i = 0; i < 4; ++i) {
        int idx = base + tid * 4 + i;
        if (idx < N) off[idx] = run;
        run += v[i];
    }
}

__global__ __launch_bounds__(256) void scan2(int* __restrict__ bsum, int nb)
{
    __shared__ int lds[256];
    int tid = threadIdx.x;
    int v = (tid < nb) ? bsum[tid] : 0;
    lds[tid] = v;
    __syncthreads();
    for (int ofs = 1; ofs < 256; ofs <<= 1) {
        int t = (tid >= ofs) ? lds[tid - ofs] : 0;
        __syncthreads();
        lds[tid] += t;
        __syncthreads();
    }
    if (tid < nb) bsum[tid] = lds[tid] - v;
}

__global__ __launch_bounds__(256) void scan3(
    int* __restrict__ off, const int* __restrict__ bsum, int N, int E)
{
    int gid = blockIdx.x * 256 + threadIdx.x;
    if (gid < N) off[gid] += bsum[gid >> 10];
    if (gid == 0) off[N] = E;
}

__global__ __launch_bounds__(256) void fill_csr(
    const int* __restrict__ row, const int* __restrict__ off,
    int* __restrict__ cursor, int* __restrict__ csr, int E, int N)
{
    int e = blockIdx.x * 256 + threadIdx.x;
    if (e >= E) return;
    int r = row[e];
    if ((unsigned)r >= (unsigned)N) return;
    int p = atomicAdd(&cursor[r], 1);
    csr[off[r] + p] = e;
}

// Fused scores+softmax+aggregate. One wave per dst node; lane holds dims
// (2*lane, 2*lane+1), head = lane>>4 (16-lane groups). K[node], D in regs.
// Per edge: gather Q|V rows of col (adjacent 1KB block), per-lane partial
// score, shfl_xor reduce within head group, ex=exp(leakyrelu(z)), accumulate
// ex*V and ex; divide once at the end. One edge prefetched ahead.
__global__ __launch_bounds__(256) void fused_aggregate(
    const int* __restrict__ col, const int* __restrict__ off,
    const int* __restrict__ csr, const float* __restrict__ QV,
    const float* __restrict__ Kb, const float* __restrict__ D,
    float* __restrict__ out, int N)
{
    int node = blockIdx.x * 4 + (threadIdx.x >> 6);
    if (node >= N) return;
    int lane = threadIdx.x & 63;
    int d = lane * 2;
    const float2 kv = *reinterpret_cast<const float2*>(Kb + (size_t)node * FDIM + d);
    const float D0 = D[d], D1 = D[d + 1];
    int j0 = off[node], j1 = off[node + 1];
    float a0 = 0.0f, a1 = 0.0f, se = 0.0f;

    if (j0 < j1) {
        int c = col[csr[j0]];
        float2 q = *reinterpret_cast<const float2*>(QV + (size_t)c * 256 + d);
        float2 v = *reinterpret_cast<const float2*>(QV + (size_t)c * 256 + FDIM + d);
        for (int j = j0; j < j1; ++j) {
            int cn = c; float2 qn = q, vn = v;
            if (j + 1 < j1) {
                cn = col[csr[j + 1]];
                qn = *reinterpret_cast<const float2*>(QV + (size_t)cn * 256 + d);
                vn = *reinterpret_cast<const float2*>(QV + (size_t)cn * 256 + FDIM + d);
            }
            float p;
            if (c == node) {
                p = D0 * kv.x * q.x + D1 * kv.y * q.y;     // self edge: K.D.Q
            } else {
                float dx = kv.x - q.x, dy = kv.y - q.y;
                p = D0 * dx * dx + D1 * dy * dy;
            }
            p += __shfl_xor(p, 1);
            p += __shfl_xor(p, 2);
            p += __shfl_xor(p, 4);
            p += __shfl_xor(p, 8);                          // head-group sum
            float z = p * 0.17677669529663687f;             // 1/sqrt(32)
            z = (z > 0.0f) ? z : 0.2f * z;                  // leaky_relu 0.2
            float ex = __expf(z);
            a0 += ex * v.x; a1 += ex * v.y; se += ex;
            c = cn; q = qn; v = vn;
        }
    }
    float inv = 1.0f / (se + 1e-16f);
    *reinterpret_cast<float2*>(out + (size_t)node * FDIM + d) =
        make_float2(a0 * inv, a1 * inv);
}

extern "C" void kernel_launch(void* const* d_in, const int* in_sizes, int n_in,
                              void* d_out, int out_size, void* d_ws, size_t ws_size,
                              hipStream_t stream) {
    const float* x  = (const float*)d_in[0];
    const float* Wq = (const float*)d_in[1];
    const float* Wk = (const float*)d_in[2];
    const float* Wv = (const float*)d_in[3];
    const float* D  = (const float*)d_in[4];
    const int*  edge = (const int*)d_in[5];
    float* out = (float*)d_out;

    const int N = in_sizes[0] / FDIM;
    const int E = in_sizes[5] / 2;
    const int* row = edge;       // edge_index[0] = destination (segment id)
    const int* col = edge + E;   // edge_index[1] = source of Q_j / V

    // Workspace: QV[N][256] | K[N][128] | deg | cursor | off | bsum | csr
    float* ws   = (float*)d_ws;
    float* QV   = ws;
    float* Kb   = QV + (size_t)N * 256;
    int* deg    = (int*)(Kb + (size_t)N * FDIM);
    int* cursor = deg + N;
    int* off    = cursor + N;          // N+1 entries
    int* bsum   = off + (N + 1);       // up to 256 entries
    int* csr    = bsum + 256;          // E entries

    const int nb = (N + 1023) / 1024;

    init_buffers<<<(N + 255) / 256, 256, 0, stream>>>(deg, cursor, N);

    dim3 ggrid((N + 127) / 128, 3);
    qkv_gemm<<<ggrid, 256, 0, stream>>>(x, Wq, Wk, Wv, QV, Kb, N);

    deg_count<<<(E + 255) / 256, 256, 0, stream>>>(row, deg, E, N);
    scan1<<<nb, 256, 0, stream>>>(deg, off, bsum, N);
    scan2<<<1, 256, 0, stream>>>(bsum, nb);
    scan3<<<(N + 255) / 256, 256, 0, stream>>>(off, bsum, N, E);
    fill_csr<<<(E + 255) / 256, 256, 0, stream>>>(row, off, cursor, csr, E, N);

    fused_aggregate<<<(N + 3) / 4, 256, 0, stream>>>(
        col, off, csr, QV, Kb, D, out, N);
}

// Round 7
// 703.403 us; speedup vs baseline: 1.8665x; 1.1079x over previous
//
#include <hip/hip_runtime.h>
#include <cmath>

// ---------------------------------------------------------------------------
// PlainGNN: Q/K/V = x@W^T ; per-edge scores = leakyrelu(scale * sum_d D*(K_i-Q_j)^2)
// (self edges: K^T diag(D) Q) ; segment-softmax over destination row ;
// out[row] += alpha * V[col].
// N=100000, E=1600000, IN_F=128, HEADS=4, D_K=32.
//
// R1: edge_aggregate atomic-bound. R2/R3: CSR by dest, one wave per node.
// R4: (256,4) spilled acc. R5: cap removed -> 1042us. R6: fused
// scores+softmax+aggregate, QV interleaved -> 779us; fused_aggregate 290us,
// latency-bound (VALU 32%, HBM 42%, 1-deep prefetch).
// R7: 4-deep static software pipeline (4 reg slots, 8 outstanding gathers)
// + csr stores col[e] directly (removes one dependent gather level).
// ---------------------------------------------------------------------------

#define HEADS 4
#define DK 32
#define FDIM 128

// deg=0, cursor=0 over N.
__global__ __launch_bounds__(256) void init_buffers(
    int* __restrict__ deg, int* __restrict__ cursor, int n)
{
    int gid = blockIdx.x * 256 + threadIdx.x;
    if (gid < n) { deg[gid] = 0; cursor[gid] = 0; }
}

// Fused QKV projection. Block = 256 threads computes a 128-node x 128-out tile
// for one of {Wq,Wk,Wv} (blockIdx.y). k-major LDS tiles (stride 132 floats
// keeps float4 alignment) -> inner loop is 4x ds_read_b128 + 64 FMA per k.
// Q and V write interleaved into QV[N][256] (Q at +0, V at +128); K dense.
// NOTE: plain launch_bounds(256) — (256,4) forced VGPR=64 and spilled (R4).
__global__ __launch_bounds__(256) void qkv_gemm(
    const float* __restrict__ x, const float* __restrict__ Wq,
    const float* __restrict__ Wk, const float* __restrict__ Wv,
    float* __restrict__ QV, float* __restrict__ Kb, int N)
{
    __shared__ float xs[32][132];
    __shared__ float ws[32][132];
    const float* __restrict__ W = (blockIdx.y == 0) ? Wq : (blockIdx.y == 1 ? Wk : Wv);
    float* __restrict__ O = (blockIdx.y == 1) ? Kb : QV;
    const int ostride = (blockIdx.y == 1) ? FDIM : 256;
    const int obase   = (blockIdx.y == 2) ? FDIM : 0;
    const int n0 = blockIdx.x * 128;
    const int tid = threadIdx.x;
    const int tm = (tid & 15) * 8;   // 8 nodes per thread
    const int tn = (tid >> 4) * 8;   // 8 outputs per thread

    float acc[8][8];
#pragma unroll
    for (int i = 0; i < 8; ++i)
#pragma unroll
        for (int j = 0; j < 8; ++j) acc[i][j] = 0.0f;

    for (int kt = 0; kt < FDIM; kt += 32) {
#pragma unroll
        for (int p = 0; p < 4; ++p) {
            int f = tid + p * 256;       // float4 id: 8 per row
            int r = f >> 3;              // row 0..127
            int kq = (f & 7) * 4;        // k offset
            int n = n0 + r;
            float4 v = make_float4(0.f, 0.f, 0.f, 0.f);
            if (n < N) v = *reinterpret_cast<const float4*>(x + (size_t)n * FDIM + kt + kq);
            xs[kq + 0][r] = v.x; xs[kq + 1][r] = v.y;
            xs[kq + 2][r] = v.z; xs[kq + 3][r] = v.w;
            float4 w4 = *reinterpret_cast<const float4*>(W + r * FDIM + kt + kq);
            ws[kq + 0][r] = w4.x; ws[kq + 1][r] = w4.y;
            ws[kq + 2][r] = w4.z; ws[kq + 3][r] = w4.w;
        }
        __syncthreads();
#pragma unroll
        for (int k = 0; k < 32; ++k) {
            float4 a0 = *reinterpret_cast<const float4*>(&xs[k][tm]);
            float4 a1 = *reinterpret_cast<const float4*>(&xs[k][tm + 4]);
            float4 b0 = *reinterpret_cast<const float4*>(&ws[k][tn]);
            float4 b1 = *reinterpret_cast<const float4*>(&ws[k][tn + 4]);
            float av[8] = {a0.x, a0.y, a0.z, a0.w, a1.x, a1.y, a1.z, a1.w};
            float bv[8] = {b0.x, b0.y, b0.z, b0.w, b1.x, b1.y, b1.z, b1.w};
#pragma unroll
            for (int i = 0; i < 8; ++i)
#pragma unroll
                for (int j = 0; j < 8; ++j) acc[i][j] += av[i] * bv[j];
        }
        __syncthreads();
    }

#pragma unroll
    for (int i = 0; i < 8; ++i) {
        int n = n0 + tm + i;
        if (n < N) {
            *reinterpret_cast<float4*>(O + (size_t)n * ostride + obase + tn) =
                make_float4(acc[i][0], acc[i][1], acc[i][2], acc[i][3]);
            *reinterpret_cast<float4*>(O + (size_t)n * ostride + obase + tn + 4) =
                make_float4(acc[i][4], acc[i][5], acc[i][6], acc[i][7]);
        }
    }
}

// ---- CSR build: degree histogram -> exclusive scan -> scatter fill ----

__global__ __launch_bounds__(256) void deg_count(
    const int* __restrict__ row, int* __restrict__ deg, int E, int N)
{
    int gid = blockIdx.x * 256 + threadIdx.x;
    if (gid >= E) return;
    int r = row[gid];
    if ((unsigned)r < (unsigned)N) atomicAdd(&deg[r], 1);
}

__global__ __launch_bounds__(256) void scan1(
    const int* __restrict__ deg, int* __restrict__ off, int* __restrict__ bsum, int N)
{
    __shared__ int lds[256];
    const int base = blockIdx.x * 1024;
    const int tid = threadIdx.x;
    int v[4];
    int tsum = 0;
#pragma unroll
    for (int i = 0; i < 4; ++i) {
        int idx = base + tid * 4 + i;
        v[i] = (idx < N) ? deg[idx] : 0;
        tsum += v[i];
    }
    lds[tid] = tsum;
    __syncthreads();
    for (int ofs = 1; ofs < 256; ofs <<= 1) {
        int t = (tid >= ofs) ? lds[tid - ofs] : 0;
        __syncthreads();
        lds[tid] += t;
        __syncthreads();
    }
    int run = lds[tid] - tsum;
    if (tid == 255) bsum[blockIdx.x] = lds[255];
#pragma unroll
    for (int i = 0; i < 4; ++i) {
        int idx = base + tid * 4 + i;
        if (idx < N) off[idx] = run;
        run += v[i];
    }
}

__global__ __launch_bounds__(256) void scan2(int* __restrict__ bsum, int nb)
{
    __shared__ int lds[256];
    int tid = threadIdx.x;
    int v = (tid < nb) ? bsum[tid] : 0;
    lds[tid] = v;
    __syncthreads();
    for (int ofs = 1; ofs < 256; ofs <<= 1) {
        int t = (tid >= ofs) ? lds[tid - ofs] : 0;
        __syncthreads();
        lds[tid] += t;
        __syncthreads();
    }
    if (tid < nb) bsum[tid] = lds[tid] - v;
}

__global__ __launch_bounds__(256) void scan3(
    int* __restrict__ off, const int* __restrict__ bsum, int N, int E)
{
    int gid = blockIdx.x * 256 + threadIdx.x;
    if (gid < N) off[gid] += bsum[gid >> 10];
    if (gid == 0) off[N] = E;
}

// csr stores the SOURCE NODE (col[e]) directly — downstream never needs the
// edge id, and this removes one dependent gather level in fused_aggregate.
__global__ __launch_bounds__(256) void fill_csr(
    const int* __restrict__ row, const int* __restrict__ col,
    const int* __restrict__ off, int* __restrict__ cursor,
    int* __restrict__ csr, int E, int N)
{
    int e = blockIdx.x * 256 + threadIdx.x;
    if (e >= E) return;
    int r = row[e];
    if ((unsigned)r >= (unsigned)N) return;
    int p = atomicAdd(&cursor[r], 1);
    csr[off[r] + p] = col[e];
}

// Fused scores+softmax+aggregate. One wave per dst node; lane holds dims
// (2*lane, 2*lane+1), head = lane>>4 (16-lane groups). K[node], D in regs.
// 4-deep static software pipeline: 4 register slots, each PROC immediately
// re-issues its slot's next gather -> up to 8 outstanding 512B loads/wave.
__global__ __launch_bounds__(256) void fused_aggregate(
    const int* __restrict__ off, const int* __restrict__ csr,
    const float* __restrict__ QV, const float* __restrict__ Kb,
    const float* __restrict__ D, float* __restrict__ out, int N)
{
    int node = blockIdx.x * 4 + (threadIdx.x >> 6);
    if (node >= N) return;
    int lane = threadIdx.x & 63;
    int d = lane * 2;
    const float2 kv = *reinterpret_cast<const float2*>(Kb + (size_t)node * FDIM + d);
    const float D0 = D[d], D1 = D[d + 1];
    const int j0 = off[node];
    const int cnt = off[node + 1] - j0;
    float a0 = 0.0f, a1 = 0.0f, se = 0.0f;

    int   cc0, cc1, cc2, cc3;
    float2 qq0, qq1, qq2, qq3, vv0, vv1, vv2, vv3;

#define LOADE(s, idx) { int c_ = csr[j0 + (idx)]; cc##s = c_; \
    qq##s = *reinterpret_cast<const float2*>(QV + (size_t)c_ * 256 + d); \
    vv##s = *reinterpret_cast<const float2*>(QV + (size_t)c_ * 256 + FDIM + d); }

#define PROC(s) { float p; \
    if (cc##s == node) { p = D0 * kv.x * qq##s.x + D1 * kv.y * qq##s.y; } \
    else { float dx = kv.x - qq##s.x, dy = kv.y - qq##s.y; \
           p = D0 * dx * dx + D1 * dy * dy; } \
    p += __shfl_xor(p, 1); p += __shfl_xor(p, 2); \
    p += __shfl_xor(p, 4); p += __shfl_xor(p, 8); \
    float z = p * 0.17677669529663687f; \
    z = (z > 0.0f) ? z : 0.2f * z; \
    float ex = __expf(z); \
    a0 += ex * vv##s.x; a1 += ex * vv##s.y; se += ex; }

    int j = 0;
    if (cnt >= 4) {
        LOADE(0, 0) LOADE(1, 1) LOADE(2, 2) LOADE(3, 3)
        while (j + 8 <= cnt) {
            PROC(0) LOADE(0, j + 4)
            PROC(1) LOADE(1, j + 5)
            PROC(2) LOADE(2, j + 6)
            PROC(3) LOADE(3, j + 7)
            j += 4;
        }
        PROC(0) PROC(1) PROC(2) PROC(3)
        j += 4;
    }
    for (; j < cnt; ++j) {
        LOADE(0, j)
        PROC(0)
    }
#undef LOADE
#undef PROC

    float inv = 1.0f / (se + 1e-16f);
    *reinterpret_cast<float2*>(out + (size_t)node * FDIM + d) =
        make_float2(a0 * inv, a1 * inv);
}

extern "C" void kernel_launch(void* const* d_in, const int* in_sizes, int n_in,
                              void* d_out, int out_size, void* d_ws, size_t ws_size,
                              hipStream_t stream) {
    const float* x  = (const float*)d_in[0];
    const float* Wq = (const float*)d_in[1];
    const float* Wk = (const float*)d_in[2];
    const float* Wv = (const float*)d_in[3];
    const float* D  = (const float*)d_in[4];
    const int*  edge = (const int*)d_in[5];
    float* out = (float*)d_out;

    const int N = in_sizes[0] / FDIM;
    const int E = in_sizes[5] / 2;
    const int* row = edge;       // edge_index[0] = destination (segment id)
    const int* col = edge + E;   // edge_index[1] = source of Q_j / V

    // Workspace: QV[N][256] | K[N][128] | deg | cursor | off | bsum | csr
    float* ws   = (float*)d_ws;
    float* QV   = ws;
    float* Kb   = QV + (size_t)N * 256;
    int* deg    = (int*)(Kb + (size_t)N * FDIM);
    int* cursor = deg + N;
    int* off    = cursor + N;          // N+1 entries
    int* bsum   = off + (N + 1);       // up to 256 entries
    int* csr    = bsum + 256;          // E entries (source node per slot)

    const int nb = (N + 1023) / 1024;

    init_buffers<<<(N + 255) / 256, 256, 0, stream>>>(deg, cursor, N);

    dim3 ggrid((N + 127) / 128, 3);
    qkv_gemm<<<ggrid, 256, 0, stream>>>(x, Wq, Wk, Wv, QV, Kb, N);

    deg_count<<<(E + 255) / 256, 256, 0, stream>>>(row, deg, E, N);
    scan1<<<nb, 256, 0, stream>>>(deg, off, bsum, N);
    scan2<<<1, 256, 0, stream>>>(bsum, nb);
    scan3<<<(N + 255) / 256, 256, 0, stream>>>(off, bsum, N, E);
    fill_csr<<<(E + 255) / 256, 256, 0, stream>>>(row, col, off, cursor, csr, E, N);

    fused_aggregate<<<(N + 3) / 4, 256, 0, stream>>>(
        off, csr, QV, Kb, D, out, N);
}